// Round 2
// baseline (1187.736 us; speedup 1.0000x reference)
//
#include <hip/hip_runtime.h>
#include <hip/hip_bf16.h>
#include <stdint.h>

// Problem: B=2 S=2048 HIDDEN=4096 NH=32 KVH=8 D=128 GROUPS=4
// Round 2 theory: inputs are fp32 (per reference dtypes), output fp32.
// Convert once to bf16 in ws, run bf16 MFMA pipeline, store fp32 output.
// ws layout (bytes):
//   [0,            50331648)  QKV bf16 [4096][6144]
//   [50331648,     83886080)  Xb bf16 [4096][4096], later reused as ATT
//   [83886080,    117440512)  Wqb bf16 [4096][4096], later reused as Wob
//   [117440512,   125829120)  Wkb bf16 [1024][4096]
//   [125829120,   134217728)  Wvb bf16 [1024][4096]

typedef uint16_t u16;
typedef __attribute__((ext_vector_type(4))) float f32x4;
typedef __attribute__((ext_vector_type(8))) short s16x8;
typedef __attribute__((ext_vector_type(4))) short s16x4;

__device__ __forceinline__ float bf2f(u16 u) {
  union { uint32_t i; float f; } v; v.i = ((uint32_t)u) << 16; return v.f;
}
__device__ __forceinline__ u16 f2bf(float f) {
  union { uint32_t i; float f; } v; v.f = f;
  uint32_t r = v.i + 0x7FFFu + ((v.i >> 16) & 1u);
  return (u16)(r >> 16);
}
__device__ __forceinline__ void gld_lds16(const void* g, void* l) {
  __builtin_amdgcn_global_load_lds((const __attribute__((address_space(1))) void*)g,
                                   (__attribute__((address_space(3))) void*)l, 16, 0, 0);
}

// ---------------- fp32 -> bf16 conversion (vectorized, one-shot) -------------
__global__ __launch_bounds__(256) void cvt_f32_bf16(const float* __restrict__ s,
                                                    u16* __restrict__ d, int n4) {
  int i = blockIdx.x * 256 + threadIdx.x;
  if (i < n4) {
    f32x4 v = ((const f32x4*)s)[i];
    s16x4 o;
    o.x = (short)f2bf(v.x); o.y = (short)f2bf(v.y);
    o.z = (short)f2bf(v.z); o.w = (short)f2bf(v.w);
    ((s16x4*)d)[i] = o;
  }
}

// ---------------- GEMM: C[M,N] = A[M,K] * B[N,K]^T, bf16 in, fp32 accum ------
// m97 structure: 128x128 tile, BK=64, global_load_lds(16B), 16x16x32 bf16 MFMA.
#define BM 128
#define BN 128
#define BK 64

template <typename OUT>
__global__ __launch_bounds__(256) void gemm_bt(
    const u16* __restrict__ A,
    const u16* __restrict__ B0, const u16* __restrict__ B1, const u16* __restrict__ B2,
    int nb1, int nb2,
    OUT* __restrict__ C, int K, int ldc)
{
  __shared__ u16 As[BM * BK];
  __shared__ u16 Bs[BN * BK];

  const int m0 = blockIdx.y * BM;
  const int n0 = blockIdx.x * BN;
  const u16* Bp;
  if (n0 < nb1)      Bp = B0 + (size_t)n0 * K;
  else if (n0 < nb2) Bp = B1 + (size_t)(n0 - nb1) * K;
  else               Bp = B2 + (size_t)(n0 - nb2) * K;
  const u16* Ap = A + (size_t)m0 * K;

  const int tid  = threadIdx.x;
  const int wave = tid >> 6, lane = tid & 63;
  const int wm = wave & 1, wn = wave >> 1;
  const int lr = lane & 15, lg = lane >> 4;

  const int srow = wave * 8 + (lane >> 3);
  const int scol = (lane & 7) * 8;

  f32x4 acc[4][4] = {};

  for (int k0 = 0; k0 < K; k0 += BK) {
#pragma unroll
    for (int i = 0; i < 4; i++) {
      gld_lds16(Ap + (size_t)(i * 32 + srow) * K + k0 + scol,
                (char*)As + i * 4096 + wave * 1024);
      gld_lds16(Bp + (size_t)(i * 32 + srow) * K + k0 + scol,
                (char*)Bs + i * 4096 + wave * 1024);
    }
    __syncthreads();   // drains vmcnt -> LDS tiles complete
#pragma unroll
    for (int ks = 0; ks < 2; ks++) {
      s16x8 af[4], bf[4];
#pragma unroll
      for (int t = 0; t < 4; t++)
        af[t] = *(const s16x8*)&As[(wm * 64 + t * 16 + lr) * BK + ks * 32 + lg * 8];
#pragma unroll
      for (int t = 0; t < 4; t++)
        bf[t] = *(const s16x8*)&Bs[(wn * 64 + t * 16 + lr) * BK + ks * 32 + lg * 8];
#pragma unroll
      for (int mi = 0; mi < 4; mi++)
#pragma unroll
        for (int ni = 0; ni < 4; ni++)
          acc[mi][ni] = __builtin_amdgcn_mfma_f32_16x16x32_bf16(af[mi], bf[ni], acc[mi][ni], 0, 0, 0);
    }
    __syncthreads();
  }

  // epilogue: C/D layout col=lane&15, row=(lane>>4)*4+reg (m89/m91 verified)
  const int crow0 = m0 + wm * 64;
  const int ccol0 = n0 + wn * 64;
#pragma unroll
  for (int mi = 0; mi < 4; mi++)
#pragma unroll
    for (int ni = 0; ni < 4; ni++) {
      int col = ccol0 + ni * 16 + lr;
      int row = crow0 + mi * 16 + lg * 4;
#pragma unroll
      for (int r = 0; r < 4; r++) {
        float v = acc[mi][ni][r];
        if constexpr (sizeof(OUT) == 2)
          C[(size_t)(row + r) * ldc + col] = (OUT)f2bf(v);
        else
          C[(size_t)(row + r) * ldc + col] = (OUT)v;
      }
    }
}

// ---------------- RoPE in-place on QKV cols [0,5120) -------------------------
__global__ __launch_bounds__(256) void rope_kernel(u16* __restrict__ qkv,
                                                   const int* __restrict__ pos_ids)
{
  int gid  = blockIdx.x * 256 + threadIdx.x;
  int pair = gid & 63;
  int u    = gid >> 6;           // 0 .. 4096*40-1 (grid exact)
  int hh   = u % 40;
  int row  = u / 40;
  int s    = row & 2047;

  float p    = (float)pos_ids[s];
  float freq = exp2f(-(float)pair * 0.20762050593046014f);  // 10000^(-pair/64)
  float ang  = p * freq;
  float cs   = cosf(ang), sn = sinf(ang);

  size_t base = (size_t)row * 6144 + hh * 128;   // hh<32: Q head; 32..39: K head
  float x1 = bf2f(qkv[base + pair]);
  float x2 = bf2f(qkv[base + pair + 64]);
  qkv[base + pair]      = f2bf(x1 * cs - x2 * sn);
  qkv[base + pair + 64] = f2bf(x2 * cs + x1 * sn);
}

// ---------------- Flash attention (causal, GQA) ------------------------------
#define NEGI (-30000.0f)   // finite sentinel; |logits*scale*log2e| << 2000

__global__ __launch_bounds__(256) void flash_attn(const u16* __restrict__ qkv,
                                                  u16* __restrict__ attn)
{
  __shared__ u16 Ks[64 * 136];   // [kv][d], +8 pad keeps 16B row alignment
  __shared__ u16 Vt[128 * 64];   // [d][kv^swz]
  __shared__ u16 Ps[4 * 32 * 72];// per-wave [m][kv]

  const int qt = blockIdx.x;     // 0..15
  const int h  = blockIdx.y;     // 0..31
  const int b  = blockIdx.z;     // 0..1
  const int kvh = h >> 2;        // GQA groups=4

  const int tid = threadIdx.x;
  const int wave = tid >> 6, lane = tid & 63;
  const int lr = lane & 15, lg = lane >> 4;

  const size_t rs = 6144;
  const u16* Qb = qkv + (size_t)(b * 2048) * rs + h * 128;
  const u16* Kb = qkv + (size_t)(b * 2048) * rs + 4096 + kvh * 128;
  const u16* Vb = qkv + (size_t)(b * 2048) * rs + 5120 + kvh * 128;

  // preload Q frags: A-layout A[m=lane&15][k=(lane>>4)*8+j]
  s16x8 qf[2][4];
#pragma unroll
  for (int t = 0; t < 2; t++) {
    int qrow = qt * 128 + wave * 32 + t * 16 + lr;
#pragma unroll
    for (int ks = 0; ks < 4; ks++)
      qf[t][ks] = *(const s16x8*)(Qb + (size_t)qrow * rs + ks * 32 + lg * 8);
  }

  f32x4 oacc[2][8] = {};
  float mstate[2][4], lstate[2][4];
#pragma unroll
  for (int t = 0; t < 2; t++)
#pragma unroll
    for (int r = 0; r < 4; r++) { mstate[t][r] = NEGI; lstate[t][r] = 0.f; }

  const float sm_scale = 0.12751569953356377f;  // (1/sqrt(128)) * log2(e)
  const int jmax = 2 * qt + 1;
  const int d0_s = (tid & 15) * 8;

  for (int j = 0; j <= jmax; j++) {
    __syncthreads();             // previous tile's readers done
    // stage K (natural) and V (transposed+swizzled)
#pragma unroll
    for (int i = 0; i < 4; i++) {
      int kv = i * 16 + (tid >> 4);
      s16x8 kval = *(const s16x8*)(Kb + (size_t)(j * 64 + kv) * rs + d0_s);
      *(s16x8*)&Ks[kv * 136 + d0_s] = kval;
      s16x8 vval = *(const s16x8*)(Vb + (size_t)(j * 64 + kv) * rs + d0_s);
#pragma unroll
      for (int jj = 0; jj < 8; jj++) {
        int d = d0_s + jj;
        int pk = kv ^ (((d >> 3) & 7) << 3);
        Vt[d * 64 + pk] = (u16)vval[jj];
      }
    }
    __syncthreads();

    // S = Q K^T  (C-layout: row = lg*4+r within 16-tile, col = lr)
    f32x4 sacc[2][4] = {};
#pragma unroll
    for (int ks = 0; ks < 4; ks++) {
      s16x8 kf[4];
#pragma unroll
      for (int nt = 0; nt < 4; nt++)
        kf[nt] = *(const s16x8*)&Ks[(nt * 16 + lr) * 136 + ks * 32 + lg * 8];
#pragma unroll
      for (int t = 0; t < 2; t++)
#pragma unroll
        for (int nt = 0; nt < 4; nt++)
          sacc[t][nt] = __builtin_amdgcn_mfma_f32_16x16x32_bf16(qf[t][ks], kf[nt], sacc[t][nt], 0, 0, 0);
    }

    // online softmax (base-2 domain)
    const bool diag = (j >= 2 * qt);
#pragma unroll
    for (int t = 0; t < 2; t++) {
#pragma unroll
      for (int r = 0; r < 4; r++) {
        int qrow = qt * 128 + wave * 32 + t * 16 + lg * 4 + r;
        float mx = NEGI;
#pragma unroll
        for (int nt = 0; nt < 4; nt++) {
          float v = sacc[t][nt][r] * sm_scale;
          if (diag && (j * 64 + nt * 16 + lr) > qrow) v = NEGI;
          sacc[t][nt][r] = v;
          mx = fmaxf(mx, v);
        }
        mx = fmaxf(mx, __shfl_xor(mx, 1));
        mx = fmaxf(mx, __shfl_xor(mx, 2));
        mx = fmaxf(mx, __shfl_xor(mx, 4));
        mx = fmaxf(mx, __shfl_xor(mx, 8));
        mx = fmaxf(mx, mstate[t][r]);
        float alpha = exp2f(mstate[t][r] - mx);
        mstate[t][r] = mx;
        float rsum = 0.f;
#pragma unroll
        for (int nt = 0; nt < 4; nt++) {
          float p = exp2f(sacc[t][nt][r] - mx);
          sacc[t][nt][r] = p;
          rsum += p;
        }
        rsum += __shfl_xor(rsum, 1);
        rsum += __shfl_xor(rsum, 2);
        rsum += __shfl_xor(rsum, 4);
        rsum += __shfl_xor(rsum, 8);
        lstate[t][r] = lstate[t][r] * alpha + rsum;
#pragma unroll
        for (int n8 = 0; n8 < 8; n8++) oacc[t][n8][r] *= alpha;
#pragma unroll
        for (int nt = 0; nt < 4; nt++)
          Ps[wave * 2304 + (t * 16 + lg * 4 + r) * 72 + nt * 16 + lr] = f2bf(sacc[t][nt][r]);
      }
    }

    // O += P V : A-frags from Ps, B-frags from swizzled Vt (contiguous b128)
#pragma unroll
    for (int ks2 = 0; ks2 < 2; ks2++) {
      s16x8 pf[2];
#pragma unroll
      for (int t = 0; t < 2; t++)
        pf[t] = *(const s16x8*)&Ps[wave * 2304 + (t * 16 + lr) * 72 + ks2 * 32 + lg * 8];
#pragma unroll
      for (int nt = 0; nt < 8; nt++) {
        int d = nt * 16 + lr;
        int pk = (ks2 * 32 + lg * 8) ^ (((d >> 3) & 7) << 3);
        s16x8 vf = *(const s16x8*)&Vt[d * 64 + pk];
#pragma unroll
        for (int t = 0; t < 2; t++)
          oacc[t][nt] = __builtin_amdgcn_mfma_f32_16x16x32_bf16(pf[t], vf, oacc[t][nt], 0, 0, 0);
      }
    }
  }

  // epilogue: attn[b*2048+q][h*128+d] bf16
#pragma unroll
  for (int t = 0; t < 2; t++) {
    float inv[4];
#pragma unroll
    for (int r = 0; r < 4; r++) inv[r] = 1.0f / lstate[t][r];
    int qrow = qt * 128 + wave * 32 + t * 16 + lg * 4;
#pragma unroll
    for (int nt = 0; nt < 8; nt++) {
      int col = h * 128 + nt * 16 + lr;
#pragma unroll
      for (int r = 0; r < 4; r++)
        attn[(size_t)(b * 2048 + qrow + r) * 4096 + col] = f2bf(oacc[t][nt][r] * inv[r]);
    }
  }
}

extern "C" void kernel_launch(void* const* d_in, const int* in_sizes, int n_in,
                              void* d_out, int out_size, void* d_ws, size_t ws_size,
                              hipStream_t stream) {
  const float* X  = (const float*)d_in[0];   // [2,2048,4096] fp32
  const int* pos  = (const int*)d_in[1];     // [2048] int32
  const float* Wq = (const float*)d_in[2];   // [4096,4096] fp32
  const float* Wk = (const float*)d_in[3];   // [1024,4096] fp32
  const float* Wv = (const float*)d_in[4];   // [1024,4096] fp32
  const float* Wo = (const float*)d_in[5];   // [4096,4096] fp32
  float* out = (float*)d_out;                // [2,2048,4096] fp32

  u16* QKV = (u16*)d_ws;                       // 50.33 MB
  u16* Xb  = QKV + (size_t)4096 * 6144;        // 33.55 MB, reused as ATT
  u16* Wqb = Xb  + (size_t)4096 * 4096;        // 33.55 MB, reused as Wob
  u16* Wkb = Wqb + (size_t)4096 * 4096;        // 8.39 MB
  u16* Wvb = Wkb + (size_t)1024 * 4096;        // 8.39 MB
  u16* ATT = Xb;
  u16* Wob = Wqb;

  // 0) fp32 -> bf16 conversions
  cvt_f32_bf16<<<16384, 256, 0, stream>>>(X,  Xb,  4194304);
  cvt_f32_bf16<<<16384, 256, 0, stream>>>(Wq, Wqb, 4194304);
  cvt_f32_bf16<<< 4096, 256, 0, stream>>>(Wk, Wkb, 1048576);
  cvt_f32_bf16<<< 4096, 256, 0, stream>>>(Wv, Wvb, 1048576);
  // 1) fused QKV projection: [4096,4096] x [6144,4096]^T -> QKV bf16
  gemm_bt<u16><<<dim3(48, 32), 256, 0, stream>>>(Xb, Wqb, Wkb, Wvb, 4096, 5120, QKV, 4096, 6144);
  // 1b) Wo conversion into the now-dead Wqb region
  cvt_f32_bf16<<<16384, 256, 0, stream>>>(Wo, Wob, 4194304);
  // 2) RoPE on Q and K regions of QKV
  rope_kernel<<<40960, 256, 0, stream>>>(QKV, pos);
  // 3) causal GQA flash attention -> ATT (reuses Xb region)
  flash_attn<<<dim3(16, 32, 2), 256, 0, stream>>>(QKV, ATT);
  // 4) output projection: [4096,4096] x [4096,4096]^T -> fp32 out
  gemm_bt<float><<<dim3(32, 32), 256, 0, stream>>>(ATT, Wob, Wob, Wob, 1 << 30, 1 << 30, out, 4096, 4096);
}

// Round 3
// 1036.674 us; speedup vs baseline: 1.1457x; 1.1457x over previous
//
#include <hip/hip_runtime.h>
#include <hip/hip_bf16.h>
#include <stdint.h>

// Problem: B=2 S=2048 HIDDEN=4096 NH=32 KVH=8 D=128 GROUPS=4
// R3: flash_attn rebalanced (descending-qt dispatch) + software-pipelined KV
// loads. GEMM / cvt / rope identical to the R2 passing version.
// ws layout (bytes):
//   [0,            50331648)  QKV bf16 [4096][6144]
//   [50331648,     83886080)  Xb bf16 [4096][4096], later reused as ATT
//   [83886080,    117440512)  Wqb bf16 [4096][4096], later reused as Wob
//   [117440512,   125829120)  Wkb bf16 [1024][4096]
//   [125829120,   134217728)  Wvb bf16 [1024][4096]

typedef uint16_t u16;
typedef __attribute__((ext_vector_type(4))) float f32x4;
typedef __attribute__((ext_vector_type(8))) short s16x8;
typedef __attribute__((ext_vector_type(4))) short s16x4;

__device__ __forceinline__ float bf2f(u16 u) {
  union { uint32_t i; float f; } v; v.i = ((uint32_t)u) << 16; return v.f;
}
__device__ __forceinline__ u16 f2bf(float f) {
  union { uint32_t i; float f; } v; v.f = f;
  uint32_t r = v.i + 0x7FFFu + ((v.i >> 16) & 1u);
  return (u16)(r >> 16);
}
__device__ __forceinline__ void gld_lds16(const void* g, void* l) {
  __builtin_amdgcn_global_load_lds((const __attribute__((address_space(1))) void*)g,
                                   (__attribute__((address_space(3))) void*)l, 16, 0, 0);
}

// ---------------- fp32 -> bf16 conversion (vectorized, one-shot) -------------
__global__ __launch_bounds__(256) void cvt_f32_bf16(const float* __restrict__ s,
                                                    u16* __restrict__ d, int n4) {
  int i = blockIdx.x * 256 + threadIdx.x;
  if (i < n4) {
    f32x4 v = ((const f32x4*)s)[i];
    s16x4 o;
    o.x = (short)f2bf(v.x); o.y = (short)f2bf(v.y);
    o.z = (short)f2bf(v.z); o.w = (short)f2bf(v.w);
    ((s16x4*)d)[i] = o;
  }
}

// ---------------- GEMM: C[M,N] = A[M,K] * B[N,K]^T, bf16 in, fp32 accum ------
#define BM 128
#define BN 128
#define BK 64

template <typename OUT>
__global__ __launch_bounds__(256) void gemm_bt(
    const u16* __restrict__ A,
    const u16* __restrict__ B0, const u16* __restrict__ B1, const u16* __restrict__ B2,
    int nb1, int nb2,
    OUT* __restrict__ C, int K, int ldc)
{
  __shared__ u16 As[BM * BK];
  __shared__ u16 Bs[BN * BK];

  const int m0 = blockIdx.y * BM;
  const int n0 = blockIdx.x * BN;
  const u16* Bp;
  if (n0 < nb1)      Bp = B0 + (size_t)n0 * K;
  else if (n0 < nb2) Bp = B1 + (size_t)(n0 - nb1) * K;
  else               Bp = B2 + (size_t)(n0 - nb2) * K;
  const u16* Ap = A + (size_t)m0 * K;

  const int tid  = threadIdx.x;
  const int wave = tid >> 6, lane = tid & 63;
  const int wm = wave & 1, wn = wave >> 1;
  const int lr = lane & 15, lg = lane >> 4;

  const int srow = wave * 8 + (lane >> 3);
  const int scol = (lane & 7) * 8;

  f32x4 acc[4][4] = {};

  for (int k0 = 0; k0 < K; k0 += BK) {
#pragma unroll
    for (int i = 0; i < 4; i++) {
      gld_lds16(Ap + (size_t)(i * 32 + srow) * K + k0 + scol,
                (char*)As + i * 4096 + wave * 1024);
      gld_lds16(Bp + (size_t)(i * 32 + srow) * K + k0 + scol,
                (char*)Bs + i * 4096 + wave * 1024);
    }
    __syncthreads();
#pragma unroll
    for (int ks = 0; ks < 2; ks++) {
      s16x8 af[4], bf[4];
#pragma unroll
      for (int t = 0; t < 4; t++)
        af[t] = *(const s16x8*)&As[(wm * 64 + t * 16 + lr) * BK + ks * 32 + lg * 8];
#pragma unroll
      for (int t = 0; t < 4; t++)
        bf[t] = *(const s16x8*)&Bs[(wn * 64 + t * 16 + lr) * BK + ks * 32 + lg * 8];
#pragma unroll
      for (int mi = 0; mi < 4; mi++)
#pragma unroll
        for (int ni = 0; ni < 4; ni++)
          acc[mi][ni] = __builtin_amdgcn_mfma_f32_16x16x32_bf16(af[mi], bf[ni], acc[mi][ni], 0, 0, 0);
    }
    __syncthreads();
  }

  const int crow0 = m0 + wm * 64;
  const int ccol0 = n0 + wn * 64;
#pragma unroll
  for (int mi = 0; mi < 4; mi++)
#pragma unroll
    for (int ni = 0; ni < 4; ni++) {
      int col = ccol0 + ni * 16 + lr;
      int row = crow0 + mi * 16 + lg * 4;
#pragma unroll
      for (int r = 0; r < 4; r++) {
        float v = acc[mi][ni][r];
        if constexpr (sizeof(OUT) == 2)
          C[(size_t)(row + r) * ldc + col] = (OUT)f2bf(v);
        else
          C[(size_t)(row + r) * ldc + col] = (OUT)v;
      }
    }
}

// ---------------- RoPE in-place on QKV cols [0,5120) -------------------------
__global__ __launch_bounds__(256) void rope_kernel(u16* __restrict__ qkv,
                                                   const int* __restrict__ pos_ids)
{
  int gid  = blockIdx.x * 256 + threadIdx.x;
  int pair = gid & 63;
  int u    = gid >> 6;
  int hh   = u % 40;
  int row  = u / 40;
  int s    = row & 2047;

  float p    = (float)pos_ids[s];
  float freq = exp2f(-(float)pair * 0.20762050593046014f);
  float ang  = p * freq;
  float cs   = cosf(ang), sn = sinf(ang);

  size_t base = (size_t)row * 6144 + hh * 128;
  float x1 = bf2f(qkv[base + pair]);
  float x2 = bf2f(qkv[base + pair + 64]);
  qkv[base + pair]      = f2bf(x1 * cs - x2 * sn);
  qkv[base + pair + 64] = f2bf(x2 * cs + x1 * sn);
}

// ---------------- Flash attention (causal, GQA) ------------------------------
// grid (h, b, zz): qt = 15 - zz so heaviest blocks (most KV tiles) dispatch
// first -> near-zero tail. KV loads for tile j+1 issued right after staging
// barrier of tile j (global latency overlaps QK/softmax/PV compute).
#define NEGI (-30000.0f)

__global__ __launch_bounds__(256) void flash_attn(const u16* __restrict__ qkv,
                                                  u16* __restrict__ attn)
{
  __shared__ u16 Ks[64 * 136];   // [kv][d], +8 pad keeps 16B row alignment
  __shared__ u16 Vt[128 * 64];   // [d][kv^swz]
  __shared__ u16 Ps[4 * 32 * 72];// per-wave [m][kv]

  const int h  = blockIdx.x;     // 0..31
  const int b  = blockIdx.y;     // 0..1
  const int qt = 15 - blockIdx.z;// descending work order
  const int kvh = h >> 2;        // GQA groups=4

  const int tid = threadIdx.x;
  const int wave = tid >> 6, lane = tid & 63;
  const int lr = lane & 15, lg = lane >> 4;

  const size_t rs = 6144;
  const u16* Qb = qkv + (size_t)(b * 2048) * rs + h * 128;
  const u16* Kb = qkv + (size_t)(b * 2048) * rs + 4096 + kvh * 128;
  const u16* Vb = qkv + (size_t)(b * 2048) * rs + 5120 + kvh * 128;

  // preload Q frags: A-layout A[m=lane&15][k=(lane>>4)*8+j]
  s16x8 qf[2][4];
#pragma unroll
  for (int t = 0; t < 2; t++) {
    int qrow = qt * 128 + wave * 32 + t * 16 + lr;
#pragma unroll
    for (int ks = 0; ks < 4; ks++)
      qf[t][ks] = *(const s16x8*)(Qb + (size_t)qrow * rs + ks * 32 + lg * 8);
  }

  f32x4 oacc[2][8] = {};
  float mstate[2][4], lstate[2][4];
#pragma unroll
  for (int t = 0; t < 2; t++)
#pragma unroll
    for (int r = 0; r < 4; r++) { mstate[t][r] = NEGI; lstate[t][r] = 0.f; }

  const float sm_scale = 0.12751569953356377f;  // (1/sqrt(128)) * log2(e)
  const int jmax = 2 * qt + 1;
  const int d0_s = (tid & 15) * 8;
  const int kv_s = tid >> 4;     // 0..15 (with i*16 below covers 0..63)

  // pipeline registers: KV tile j in kreg/vreg
  s16x8 kreg[4], vreg[4];
#pragma unroll
  for (int i = 0; i < 4; i++) {
    int kv = i * 16 + kv_s;
    kreg[i] = *(const s16x8*)(Kb + (size_t)kv * rs + d0_s);
    vreg[i] = *(const s16x8*)(Vb + (size_t)kv * rs + d0_s);
  }

  for (int j = 0; j <= jmax; j++) {
    __syncthreads();             // previous tile's readers done
    // stage K (natural) and V (transposed+swizzled) from pipeline regs
#pragma unroll
    for (int i = 0; i < 4; i++) {
      int kv = i * 16 + kv_s;
      *(s16x8*)&Ks[kv * 136 + d0_s] = kreg[i];
#pragma unroll
      for (int jj = 0; jj < 8; jj++) {
        int d = d0_s + jj;
        int pk = kv ^ (((d >> 3) & 7) << 3);
        Vt[d * 64 + pk] = (u16)vreg[i][jj];
      }
    }
    __syncthreads();

    // issue next tile's global loads; retire during compute below
    if (j < jmax) {
#pragma unroll
      for (int i = 0; i < 4; i++) {
        int kv = (j + 1) * 64 + i * 16 + kv_s;
        kreg[i] = *(const s16x8*)(Kb + (size_t)kv * rs + d0_s);
        vreg[i] = *(const s16x8*)(Vb + (size_t)kv * rs + d0_s);
      }
    }

    // S = Q K^T  (C-layout: row = lg*4+r within 16-tile, col = lr)
    f32x4 sacc[2][4] = {};
#pragma unroll
    for (int ks = 0; ks < 4; ks++) {
      s16x8 kf[4];
#pragma unroll
      for (int nt = 0; nt < 4; nt++)
        kf[nt] = *(const s16x8*)&Ks[(nt * 16 + lr) * 136 + ks * 32 + lg * 8];
#pragma unroll
      for (int t = 0; t < 2; t++)
#pragma unroll
        for (int nt = 0; nt < 4; nt++)
          sacc[t][nt] = __builtin_amdgcn_mfma_f32_16x16x32_bf16(qf[t][ks], kf[nt], sacc[t][nt], 0, 0, 0);
    }

    // online softmax (base-2 domain)
    const bool diag = (j >= 2 * qt);
#pragma unroll
    for (int t = 0; t < 2; t++) {
#pragma unroll
      for (int r = 0; r < 4; r++) {
        int qrow = qt * 128 + wave * 32 + t * 16 + lg * 4 + r;
        float mx = NEGI;
#pragma unroll
        for (int nt = 0; nt < 4; nt++) {
          float v = sacc[t][nt][r] * sm_scale;
          if (diag && (j * 64 + nt * 16 + lr) > qrow) v = NEGI;
          sacc[t][nt][r] = v;
          mx = fmaxf(mx, v);
        }
        mx = fmaxf(mx, __shfl_xor(mx, 1));
        mx = fmaxf(mx, __shfl_xor(mx, 2));
        mx = fmaxf(mx, __shfl_xor(mx, 4));
        mx = fmaxf(mx, __shfl_xor(mx, 8));
        mx = fmaxf(mx, mstate[t][r]);
        float alpha = exp2f(mstate[t][r] - mx);
        mstate[t][r] = mx;
        float rsum = 0.f;
#pragma unroll
        for (int nt = 0; nt < 4; nt++) {
          float p = exp2f(sacc[t][nt][r] - mx);
          sacc[t][nt][r] = p;
          rsum += p;
        }
        rsum += __shfl_xor(rsum, 1);
        rsum += __shfl_xor(rsum, 2);
        rsum += __shfl_xor(rsum, 4);
        rsum += __shfl_xor(rsum, 8);
        lstate[t][r] = lstate[t][r] * alpha + rsum;
#pragma unroll
        for (int n8 = 0; n8 < 8; n8++) oacc[t][n8][r] *= alpha;
#pragma unroll
        for (int nt = 0; nt < 4; nt++)
          Ps[wave * 2304 + (t * 16 + lg * 4 + r) * 72 + nt * 16 + lr] = f2bf(sacc[t][nt][r]);
      }
    }

    // O += P V : A-frags from Ps, B-frags from swizzled Vt (contiguous b128)
#pragma unroll
    for (int ks2 = 0; ks2 < 2; ks2++) {
      s16x8 pf[2];
#pragma unroll
      for (int t = 0; t < 2; t++)
        pf[t] = *(const s16x8*)&Ps[wave * 2304 + (t * 16 + lr) * 72 + ks2 * 32 + lg * 8];
#pragma unroll
      for (int nt = 0; nt < 8; nt++) {
        int d = nt * 16 + lr;
        int pk = (ks2 * 32 + lg * 8) ^ (((d >> 3) & 7) << 3);
        s16x8 vf = *(const s16x8*)&Vt[d * 64 + pk];
#pragma unroll
        for (int t = 0; t < 2; t++)
          oacc[t][nt] = __builtin_amdgcn_mfma_f32_16x16x32_bf16(pf[t], vf, oacc[t][nt], 0, 0, 0);
      }
    }
  }

  // epilogue: attn[b*2048+q][h*128+d] bf16
#pragma unroll
  for (int t = 0; t < 2; t++) {
    float inv[4];
#pragma unroll
    for (int r = 0; r < 4; r++) inv[r] = 1.0f / lstate[t][r];
    int qrow = qt * 128 + wave * 32 + t * 16 + lg * 4;
#pragma unroll
    for (int nt = 0; nt < 8; nt++) {
      int col = h * 128 + nt * 16 + lr;
#pragma unroll
      for (int r = 0; r < 4; r++)
        attn[(size_t)(b * 2048 + qrow + r) * 4096 + col] = f2bf(oacc[t][nt][r] * inv[r]);
    }
  }
}

extern "C" void kernel_launch(void* const* d_in, const int* in_sizes, int n_in,
                              void* d_out, int out_size, void* d_ws, size_t ws_size,
                              hipStream_t stream) {
  const float* X  = (const float*)d_in[0];   // [2,2048,4096] fp32
  const int* pos  = (const int*)d_in[1];     // [2048] int32
  const float* Wq = (const float*)d_in[2];   // [4096,4096] fp32
  const float* Wk = (const float*)d_in[3];   // [1024,4096] fp32
  const float* Wv = (const float*)d_in[4];   // [1024,4096] fp32
  const float* Wo = (const float*)d_in[5];   // [4096,4096] fp32
  float* out = (float*)d_out;                // [2,2048,4096] fp32

  u16* QKV = (u16*)d_ws;                       // 50.33 MB
  u16* Xb  = QKV + (size_t)4096 * 6144;        // reused as ATT
  u16* Wqb = Xb  + (size_t)4096 * 4096;        // reused as Wob
  u16* Wkb = Wqb + (size_t)4096 * 4096;
  u16* Wvb = Wkb + (size_t)1024 * 4096;
  u16* ATT = Xb;
  u16* Wob = Wqb;

  // 0) fp32 -> bf16 conversions
  cvt_f32_bf16<<<16384, 256, 0, stream>>>(X,  Xb,  4194304);
  cvt_f32_bf16<<<16384, 256, 0, stream>>>(Wq, Wqb, 4194304);
  cvt_f32_bf16<<< 4096, 256, 0, stream>>>(Wk, Wkb, 1048576);
  cvt_f32_bf16<<< 4096, 256, 0, stream>>>(Wv, Wvb, 1048576);
  // 1) fused QKV projection: [4096,4096] x [6144,4096]^T -> QKV bf16
  gemm_bt<u16><<<dim3(48, 32), 256, 0, stream>>>(Xb, Wqb, Wkb, Wvb, 4096, 5120, QKV, 4096, 6144);
  // 1b) Wo conversion into the now-dead Wqb region
  cvt_f32_bf16<<<16384, 256, 0, stream>>>(Wo, Wob, 4194304);
  // 2) RoPE on Q and K regions of QKV
  rope_kernel<<<40960, 256, 0, stream>>>(QKV, pos);
  // 3) causal GQA flash attention -> ATT (descending-qt dispatch)
  flash_attn<<<dim3(32, 2, 16), 256, 0, stream>>>(QKV, ATT);
  // 4) output projection: [4096,4096] x [4096,4096]^T -> fp32 out
  gemm_bt<float><<<dim3(32, 32), 256, 0, stream>>>(ATT, Wob, Wob, Wob, 1 << 30, 1 << 30, out, 4096, 4096);
}

// Round 5
// 914.390 us; speedup vs baseline: 1.2989x; 1.1337x over previous
//
#include <hip/hip_runtime.h>
#include <hip/hip_bf16.h>
#include <stdint.h>

// Problem: B=2 S=2048 HIDDEN=4096 NH=32 KVH=8 D=128 GROUPS=4
// R5: R4 transposed-score flash_attn with the rogue placeholder loop removed
// (it was zeroing p[0..14] before the max). GEMM/cvt/rope identical to R3.

typedef uint16_t u16;
typedef __attribute__((ext_vector_type(4))) float f32x4;
typedef __attribute__((ext_vector_type(8))) short s16x8;
typedef __attribute__((ext_vector_type(4))) short s16x4;

__device__ __forceinline__ float bf2f(u16 u) {
  union { uint32_t i; float f; } v; v.i = ((uint32_t)u) << 16; return v.f;
}
__device__ __forceinline__ u16 f2bf(float f) {
  union { uint32_t i; float f; } v; v.f = f;
  uint32_t r = v.i + 0x7FFFu + ((v.i >> 16) & 1u);
  return (u16)(r >> 16);
}
__device__ __forceinline__ void gld_lds16(const void* g, void* l) {
  __builtin_amdgcn_global_load_lds((const __attribute__((address_space(1))) void*)g,
                                   (__attribute__((address_space(3))) void*)l, 16, 0, 0);
}

// ---------------- fp32 -> bf16 conversion (vectorized, one-shot) -------------
__global__ __launch_bounds__(256) void cvt_f32_bf16(const float* __restrict__ s,
                                                    u16* __restrict__ d, int n4) {
  int i = blockIdx.x * 256 + threadIdx.x;
  if (i < n4) {
    f32x4 v = ((const f32x4*)s)[i];
    s16x4 o;
    o.x = (short)f2bf(v.x); o.y = (short)f2bf(v.y);
    o.z = (short)f2bf(v.z); o.w = (short)f2bf(v.w);
    ((s16x4*)d)[i] = o;
  }
}

// ---------------- GEMM: C[M,N] = A[M,K] * B[N,K]^T, bf16 in, fp32 accum ------
#define BM 128
#define BN 128
#define BK 64

template <typename OUT>
__global__ __launch_bounds__(256) void gemm_bt(
    const u16* __restrict__ A,
    const u16* __restrict__ B0, const u16* __restrict__ B1, const u16* __restrict__ B2,
    int nb1, int nb2,
    OUT* __restrict__ C, int K, int ldc)
{
  __shared__ u16 As[BM * BK];
  __shared__ u16 Bs[BN * BK];

  const int m0 = blockIdx.y * BM;
  const int n0 = blockIdx.x * BN;
  const u16* Bp;
  if (n0 < nb1)      Bp = B0 + (size_t)n0 * K;
  else if (n0 < nb2) Bp = B1 + (size_t)(n0 - nb1) * K;
  else               Bp = B2 + (size_t)(n0 - nb2) * K;
  const u16* Ap = A + (size_t)m0 * K;

  const int tid  = threadIdx.x;
  const int wave = tid >> 6, lane = tid & 63;
  const int wm = wave & 1, wn = wave >> 1;
  const int lr = lane & 15, lg = lane >> 4;

  const int srow = wave * 8 + (lane >> 3);
  const int scol = (lane & 7) * 8;

  f32x4 acc[4][4] = {};

  for (int k0 = 0; k0 < K; k0 += BK) {
#pragma unroll
    for (int i = 0; i < 4; i++) {
      gld_lds16(Ap + (size_t)(i * 32 + srow) * K + k0 + scol,
                (char*)As + i * 4096 + wave * 1024);
      gld_lds16(Bp + (size_t)(i * 32 + srow) * K + k0 + scol,
                (char*)Bs + i * 4096 + wave * 1024);
    }
    __syncthreads();
#pragma unroll
    for (int ks = 0; ks < 2; ks++) {
      s16x8 af[4], bf[4];
#pragma unroll
      for (int t = 0; t < 4; t++)
        af[t] = *(const s16x8*)&As[(wm * 64 + t * 16 + lr) * BK + ks * 32 + lg * 8];
#pragma unroll
      for (int t = 0; t < 4; t++)
        bf[t] = *(const s16x8*)&Bs[(wn * 64 + t * 16 + lr) * BK + ks * 32 + lg * 8];
#pragma unroll
      for (int mi = 0; mi < 4; mi++)
#pragma unroll
        for (int ni = 0; ni < 4; ni++)
          acc[mi][ni] = __builtin_amdgcn_mfma_f32_16x16x32_bf16(af[mi], bf[ni], acc[mi][ni], 0, 0, 0);
    }
    __syncthreads();
  }

  const int crow0 = m0 + wm * 64;
  const int ccol0 = n0 + wn * 64;
#pragma unroll
  for (int mi = 0; mi < 4; mi++)
#pragma unroll
    for (int ni = 0; ni < 4; ni++) {
      int col = ccol0 + ni * 16 + lr;
      int row = crow0 + mi * 16 + lg * 4;
#pragma unroll
      for (int r = 0; r < 4; r++) {
        float v = acc[mi][ni][r];
        if constexpr (sizeof(OUT) == 2)
          C[(size_t)(row + r) * ldc + col] = (OUT)f2bf(v);
        else
          C[(size_t)(row + r) * ldc + col] = (OUT)v;
      }
    }
}

// ---------------- RoPE in-place on QKV cols [0,5120) -------------------------
__global__ __launch_bounds__(256) void rope_kernel(u16* __restrict__ qkv,
                                                   const int* __restrict__ pos_ids)
{
  int gid  = blockIdx.x * 256 + threadIdx.x;
  int pair = gid & 63;
  int u    = gid >> 6;
  int hh   = u % 40;
  int row  = u / 40;
  int s    = row & 2047;

  float p    = (float)pos_ids[s];
  float freq = exp2f(-(float)pair * 0.20762050593046014f);
  float ang  = p * freq;
  float cs   = cosf(ang), sn = sinf(ang);

  size_t base = (size_t)row * 6144 + hh * 128;
  float x1 = bf2f(qkv[base + pair]);
  float x2 = bf2f(qkv[base + pair + 64]);
  qkv[base + pair]      = f2bf(x1 * cs - x2 * sn);
  qkv[base + pair + 64] = f2bf(x2 * cs + x1 * sn);
}

// ---------------- Flash attention (causal, GQA), transposed scores -----------
// St = K*Q^T: lane holds St[kv = mt*16+lg*4+r][q = nt*16+lr] -> softmax over kv
// is 16 in-lane values + 2 shfl (over lg). P^T (C-layout) writes Ps[q][kv] as
// b64; PV reads it back as the exact B-operand layout for Ot = V^T*P^T (b128).
// Ot C-layout: lane holds q=nt*16+lr, d=dt*16+lg*4+r -> 8B packed stores.
#define NEGI (-30000.0f)
#define VTS 72   /* Vt row stride (halfwords) */
#define PSS 72   /* Ps row stride */

__global__ __launch_bounds__(256) void flash_attn(const u16* __restrict__ qkv,
                                                  u16* __restrict__ attn)
{
  __shared__ u16 Ks[64 * 136];       // [kv][d] natural
  __shared__ u16 Vt[128 * VTS];      // [d][kv ^ swz]
  __shared__ u16 Ps[4 * 32 * PSS];   // per-wave [q][kv]

  const int h  = blockIdx.x;     // 0..31
  const int b  = blockIdx.y;     // 0..1
  const int qt = 15 - blockIdx.z;// descending work order
  const int kvh = h >> 2;        // GQA groups=4

  const int tid = threadIdx.x;
  const int wave = tid >> 6, lane = tid & 63;
  const int lr = lane & 15, lg = lane >> 4;

  const size_t rs = 6144;
  const u16* Qb = qkv + (size_t)(b * 2048) * rs + h * 128;
  const u16* Kb = qkv + (size_t)(b * 2048) * rs + 4096 + kvh * 128;
  const u16* Vb = qkv + (size_t)(b * 2048) * rs + 5120 + kvh * 128;

  // Q fragments, B-operand layout: Q[q = wave*32+nt*16+lr][d = ks*32+lg*8+j]
  s16x8 qf[2][4];
#pragma unroll
  for (int nt = 0; nt < 2; nt++) {
    int qrow = qt * 128 + wave * 32 + nt * 16 + lr;
#pragma unroll
    for (int ks = 0; ks < 4; ks++)
      qf[nt][ks] = *(const s16x8*)(Qb + (size_t)qrow * rs + ks * 32 + lg * 8);
  }

  f32x4 oacc[8][2] = {};          // [dt][nt], Ot C-layout
  float mstate[2], lstate[2];
#pragma unroll
  for (int nt = 0; nt < 2; nt++) { mstate[nt] = NEGI; lstate[nt] = 0.f; }

  const float sm_scale = 0.12751569953356377f;  // (1/sqrt(128)) * log2(e)
  const int jmax = 2 * qt + 1;
  const int d0_s = (tid & 15) * 8;
  const int kv_s = tid >> 4;     // 0..15 across block

  // pipeline registers: KV tile j
  s16x8 kreg[4], vreg[4];
#pragma unroll
  for (int i = 0; i < 4; i++) {
    int kv = i * 16 + kv_s;
    kreg[i] = *(const s16x8*)(Kb + (size_t)kv * rs + d0_s);
    vreg[i] = *(const s16x8*)(Vb + (size_t)kv * rs + d0_s);
  }

  for (int j = 0; j <= jmax; j++) {
    __syncthreads();             // previous tile's readers done
#pragma unroll
    for (int i = 0; i < 4; i++) {
      int kv = i * 16 + kv_s;
      *(s16x8*)&Ks[kv * 136 + d0_s] = kreg[i];
#pragma unroll
      for (int jj = 0; jj < 8; jj++) {
        int d = d0_s + jj;
        int pk = kv ^ (((d >> 3) & 7) << 3);
        Vt[d * VTS + pk] = (u16)vreg[i][jj];
      }
    }
    __syncthreads();

    // prefetch next tile's KV into regs; retires during compute
    if (j < jmax) {
#pragma unroll
      for (int i = 0; i < 4; i++) {
        int kv = (j + 1) * 64 + i * 16 + kv_s;
        kreg[i] = *(const s16x8*)(Kb + (size_t)kv * rs + d0_s);
        vreg[i] = *(const s16x8*)(Vb + (size_t)kv * rs + d0_s);
      }
    }

    // St = K*Q^T: sacc[mt][nt], lane: kv = mt*16+lg*4+r, q = nt*16+lr
    f32x4 sacc[4][2] = {};
#pragma unroll
    for (int ks = 0; ks < 4; ks++) {
      s16x8 kf[4];
#pragma unroll
      for (int mt = 0; mt < 4; mt++)
        kf[mt] = *(const s16x8*)&Ks[(mt * 16 + lr) * 136 + ks * 32 + lg * 8];
#pragma unroll
      for (int mt = 0; mt < 4; mt++)
#pragma unroll
        for (int nt = 0; nt < 2; nt++)
          sacc[mt][nt] = __builtin_amdgcn_mfma_f32_16x16x32_bf16(kf[mt], qf[nt][ks], sacc[mt][nt], 0, 0, 0);
    }

    // online softmax over kv: 16 in-lane values + 2 shfl (lg dimension)
    const bool diag = (j >= 2 * qt);
#pragma unroll
    for (int nt = 0; nt < 2; nt++) {
      const int qg = qt * 128 + wave * 32 + nt * 16 + lr;
      float p[16];
#pragma unroll
      for (int mt = 0; mt < 4; mt++)
#pragma unroll
        for (int r = 0; r < 4; r++) {
          float v = sacc[mt][nt][r] * sm_scale;
          int kvg = j * 64 + mt * 16 + lg * 4 + r;
          if (diag && kvg > qg) v = NEGI;
          p[mt * 4 + r] = v;
        }
      float mx;
      {
        float a0 = fmaxf(fmaxf(p[0], p[1]), fmaxf(p[2], p[3]));
        float a1 = fmaxf(fmaxf(p[4], p[5]), fmaxf(p[6], p[7]));
        float a2 = fmaxf(fmaxf(p[8], p[9]), fmaxf(p[10], p[11]));
        float a3 = fmaxf(fmaxf(p[12], p[13]), fmaxf(p[14], p[15]));
        mx = fmaxf(fmaxf(a0, a1), fmaxf(a2, a3));
      }
      mx = fmaxf(mx, __shfl_xor(mx, 16));
      mx = fmaxf(mx, __shfl_xor(mx, 32));
      mx = fmaxf(mx, mstate[nt]);
      float alpha = exp2f(mstate[nt] - mx);
      mstate[nt] = mx;
      float e[16];
      float rsum;
#pragma unroll
      for (int i = 0; i < 16; i++) e[i] = exp2f(p[i] - mx);
      {
        float s0 = (e[0] + e[1]) + (e[2] + e[3]);
        float s1 = (e[4] + e[5]) + (e[6] + e[7]);
        float s2 = (e[8] + e[9]) + (e[10] + e[11]);
        float s3 = (e[12] + e[13]) + (e[14] + e[15]);
        rsum = (s0 + s1) + (s2 + s3);
      }
      rsum += __shfl_xor(rsum, 16);
      rsum += __shfl_xor(rsum, 32);
      lstate[nt] = lstate[nt] * alpha + rsum;
#pragma unroll
      for (int dt = 0; dt < 8; dt++)
        oacc[dt][nt] *= alpha;
      // P^T -> Ps[q][kv]: 4 consecutive kv per (mt) -> b64 stores
#pragma unroll
      for (int mt = 0; mt < 4; mt++) {
        s16x4 pk4;
        pk4.x = (short)f2bf(e[mt * 4 + 0]);
        pk4.y = (short)f2bf(e[mt * 4 + 1]);
        pk4.z = (short)f2bf(e[mt * 4 + 2]);
        pk4.w = (short)f2bf(e[mt * 4 + 3]);
        *(s16x4*)&Ps[wave * (32 * PSS) + (nt * 16 + lr) * PSS + mt * 16 + lg * 4] = pk4;
      }
    }

    // Ot += V^T * P^T : A-frag = Vt[d][kv] (b128), B-frag = Ps[q][kv] (b128)
#pragma unroll
    for (int c = 0; c < 2; c++) {
      s16x8 pf[2];
#pragma unroll
      for (int nt = 0; nt < 2; nt++)
        pf[nt] = *(const s16x8*)&Ps[wave * (32 * PSS) + (nt * 16 + lr) * PSS + c * 32 + lg * 8];
#pragma unroll
      for (int dt = 0; dt < 8; dt++) {
        int d = dt * 16 + lr;
        int kv0 = (c * 32 + lg * 8) ^ (((d >> 3) & 7) << 3);
        s16x8 vf = *(const s16x8*)&Vt[d * VTS + kv0];
#pragma unroll
        for (int nt = 0; nt < 2; nt++)
          oacc[dt][nt] = __builtin_amdgcn_mfma_f32_16x16x32_bf16(vf, pf[nt], oacc[dt][nt], 0, 0, 0);
      }
    }
  }

  // epilogue: Ot lane holds q = nt*16+lr, d = dt*16+lg*4+r -> ushort4 stores
#pragma unroll
  for (int nt = 0; nt < 2; nt++) {
    float inv = 1.0f / lstate[nt];
    int qrow = b * 2048 + qt * 128 + wave * 32 + nt * 16 + lr;
#pragma unroll
    for (int dt = 0; dt < 8; dt++) {
      s16x4 o4;
      o4.x = (short)f2bf(oacc[dt][nt][0] * inv);
      o4.y = (short)f2bf(oacc[dt][nt][1] * inv);
      o4.z = (short)f2bf(oacc[dt][nt][2] * inv);
      o4.w = (short)f2bf(oacc[dt][nt][3] * inv);
      *(s16x4*)&attn[(size_t)qrow * 4096 + h * 128 + dt * 16 + lg * 4] = o4;
    }
  }
}

extern "C" void kernel_launch(void* const* d_in, const int* in_sizes, int n_in,
                              void* d_out, int out_size, void* d_ws, size_t ws_size,
                              hipStream_t stream) {
  const float* X  = (const float*)d_in[0];   // [2,2048,4096] fp32
  const int* pos  = (const int*)d_in[1];     // [2048] int32
  const float* Wq = (const float*)d_in[2];   // [4096,4096] fp32
  const float* Wk = (const float*)d_in[3];   // [1024,4096] fp32
  const float* Wv = (const float*)d_in[4];   // [1024,4096] fp32
  const float* Wo = (const float*)d_in[5];   // [4096,4096] fp32
  float* out = (float*)d_out;                // [2,2048,4096] fp32

  u16* QKV = (u16*)d_ws;                       // 50.33 MB
  u16* Xb  = QKV + (size_t)4096 * 6144;        // reused as ATT
  u16* Wqb = Xb  + (size_t)4096 * 4096;        // reused as Wob
  u16* Wkb = Wqb + (size_t)4096 * 4096;
  u16* Wvb = Wkb + (size_t)1024 * 4096;
  u16* ATT = Xb;
  u16* Wob = Wqb;

  // 0) fp32 -> bf16 conversions
  cvt_f32_bf16<<<16384, 256, 0, stream>>>(X,  Xb,  4194304);
  cvt_f32_bf16<<<16384, 256, 0, stream>>>(Wq, Wqb, 4194304);
  cvt_f32_bf16<<< 4096, 256, 0, stream>>>(Wk, Wkb, 1048576);
  cvt_f32_bf16<<< 4096, 256, 0, stream>>>(Wv, Wvb, 1048576);
  // 1) fused QKV projection: [4096,4096] x [6144,4096]^T -> QKV bf16
  gemm_bt<u16><<<dim3(48, 32), 256, 0, stream>>>(Xb, Wqb, Wkb, Wvb, 4096, 5120, QKV, 4096, 6144);
  // 1b) Wo conversion into the now-dead Wqb region
  cvt_f32_bf16<<<16384, 256, 0, stream>>>(Wo, Wob, 4194304);
  // 2) RoPE on Q and K regions of QKV
  rope_kernel<<<40960, 256, 0, stream>>>(QKV, pos);
  // 3) causal GQA flash attention -> ATT (descending-qt dispatch)
  flash_attn<<<dim3(32, 2, 16), 256, 0, stream>>>(QKV, ATT);
  // 4) output projection: [4096,4096] x [4096,4096]^T -> fp32 out
  gemm_bt<float><<<dim3(32, 32), 256, 0, stream>>>(ATT, Wob, Wob, Wob, 1 << 30, 1 << 30, out, 4096, 4096);
}